// Round 7
// baseline (219.722 us; speedup 1.0000x reference)
//
#include <hip/hip_runtime.h>
#include <cstdint>
#include <cstddef>

// Problem constants
#define B_    128   // batch
#define C_    32    // in channels
#define O_    64    // out channels
#define H_    34    // input H=W (34 = 32+2)
#define NPOS  1024  // 32*32 spatial positions
#define K9    9     // 3x3 taps
#define BC    (B_ * C_)   // 4096
#define NPK   (NPOS * K9) // 9216 floats per (o,c) weight row

typedef __bf16 v8bf __attribute__((ext_vector_type(8)));
typedef float  v4f  __attribute__((ext_vector_type(4)));
typedef float  f4a  __attribute__((ext_vector_type(4)));              // 16-B aligned float4

__device__ __forceinline__ unsigned short f2bf(float f) {
    union { float f; unsigned int u; } v; v.f = f;
    unsigned int u = v.u;
    return (unsigned short)((u + 0x7FFFu + ((u >> 16) & 1u)) >> 16);
}

// 16-B global -> LDS DMA (no VGPR round-trip; dest = wave-uniform base + lane*16)
__device__ __forceinline__ void dma16(const void* g, void* l) {
    __builtin_amdgcn_global_load_lds(
        (const __attribute__((address_space(1))) unsigned int*)g,
        (__attribute__((address_space(3))) unsigned int*)l, 16, 0, 0);
}

// ---------------------------------------------------------------------------
// Pass 1: repack x (fp32 [b][c][34][34]) -> x2 (bf16 [h][w][b][c]).  [unchanged]
// ---------------------------------------------------------------------------
__global__ __launch_bounds__(256) void repack_x(const float* __restrict__ x,
                                                unsigned short* __restrict__ x2) {
    const int bq = blockIdx.x / 17;      // b-pair 0..63
    const int hp = blockIdx.x % 17;      // h-pair 0..16
    const int b0 = bq * 2;
    const int h0 = hp * 2;
    __shared__ unsigned short tile[2][H_][66];   // [hh][w][bb*32+c] (+2 pad)
    const int t = threadIdx.x;

    for (int e = t; e < 2176; e += 256) {
        const int bb  = e / 1088;
        const int rem = e % 1088;
        const int c   = rem / 34;
        const int wp  = rem % 34;        // float2 index within the 68-float run
        const float2 v = *(const float2*)(x +
            ((size_t)((b0 + bb) * C_ + c) * H_ + h0) * H_ + wp * 2);
        const int hh = (wp >= 17) ? 1 : 0;
        const int w  = wp * 2 - hh * 34;
        const int idx = bb * 32 + c;
        tile[hh][w][idx]     = f2bf(v.x);
        tile[hh][w + 1][idx] = f2bf(v.y);
    }
    __syncthreads();

    for (int e = t; e < 2176; e += 256) {
        const int hh  = e / 1088;
        const int rem = e % 1088;
        const int w   = rem >> 5;
        const int i2  = rem & 31;
        ushort2 pk;
        pk.x = tile[hh][w][i2 * 2];
        pk.y = tile[hh][w][i2 * 2 + 1];
        *(ushort2*)(x2 + (size_t)((h0 + hh) * H_ + w) * BC + bq * 64 + i2 * 2) = pk;
    }
}

// ---------------------------------------------------------------------------
// Main (v8): DMA-pipelined weight staging (global_load_lds, counted vmcnt,
// never drained).  Block = (i, 4-j, o-half of 32); grid 512; each weight byte
// staged exactly once device-wide.
// 9 granule-phases: phase p DMAs granule d4=p (16 B = floats d=4p..4p+3) for
// all 1024 pl (pl = o_local*32 + c) into fp32 scratch (dbuf 2x16 KB), then a
// short VALU pass converts to a bf16 image Im[4][1024] (writes 2-lane/bank =
// free), then 8 dense 1-KB frag reads + 8 MFMA accumulate.  Raw s_barrier +
// counted "s_waitcnt vmcnt(6)" keeps next-phase DMA in flight across barriers
// (T3/T4); ax loads issued BEFORE the DMA prefetch so compiler-inserted waits
// for them never drain it.  LDS 40 KB, __launch_bounds__(512,4) -> 2
// blocks/CU: one block computes while the other waits on DMA.
// Epilogue: fp32 out[b][o][pos] + bias, 16-B aligned runs.
// ---------------------------------------------------------------------------
__global__ __launch_bounds__(512, 4) void lc_fused8(const unsigned short* __restrict__ x2,
                                                    const float* __restrict__ weight,
                                                    const float* __restrict__ bias,
                                                    float* __restrict__ out) {
    __shared__ __align__(16) float          Ws[2][1024 * 4];   // 32,768 B fp32 scratch
    __shared__ __align__(16) unsigned short Im[4][1024];       //  8,192 B bf16 image

    const int bid = blockIdx.x;
    const int lb  = (bid & 7) * 64 + (bid >> 3);   // bijective (512 % 8 == 0)
    const int i   = lb >> 4;            // 0..31
    const int jq  = (lb >> 1) & 7;      // 0..7  (4-j group)
    const int oh  = lb & 1;             // 0..1  (32-o half)
    const int j0  = jq * 4;
    const int o0  = oh * 32;
    const int posbase = i * 32 + j0;    // multiple of 4 -> 16-B aligned out runs
    const int t  = threadIdx.x;         // 0..511
    const int wv = t >> 6;              // wave 0..7 -> b-band [wv*16, wv*16+16)
    const int l  = t & 63;
    const int lm = l & 15;              // A m-index (b) / B n-index (o)
    const int q  = l >> 4;

    // weight rows for this block: p_global = o0*32 + pl, pl = o_local*32 + c
    const float* wbase = weight + (size_t)(o0 * C_) * NPK + (size_t)posbase * K9;

    // ---- prologue: DMA phase 0 (2 instr/thread, 1024 granules) ----
#pragma unroll
    for (int m = 0; m < 2; ++m)
        dma16(wbase + (size_t)(m * 512 + t) * NPK,
              &Ws[0][(m * 512 + (wv * 64)) * 4]);

    v4f acc[4][2];                      // [jj][nt]
#pragma unroll
    for (int a = 0; a < 4; ++a)
#pragma unroll
        for (int n = 0; n < 2; ++n) acc[a][n] = (v4f){0.f, 0.f, 0.f, 0.f};

#pragma unroll
    for (int p = 0; p < 9; ++p) {
        // ---- ax loads for this phase (issued FIRST: compiler waits for these
        //      allow the 2 newer DMA prefetches to stay outstanding) ----
        v8bf ax[4];
#pragma unroll
        for (int u = 0; u < 4; ++u) {
            const int d   = p * 4 + u;            // 0..35
            const int jj  = d / 9;
            const int tap = d % 9;
            const int kh  = tap / 3, kw = tap % 3;
            const int row = (i + kh) * H_ + j0 + kw + jj;
            ax[u] = *(const v8bf*)(x2 + (size_t)row * BC + (wv * 16 + lm) * C_ + q * 8);
        }
        // ---- prefetch DMA for phase p+1, then counted wait for phase p ----
        if (p < 8) {
#pragma unroll
            for (int m = 0; m < 2; ++m)
                dma16(wbase + (size_t)(m * 512 + t) * NPK + (p + 1) * 4,
                      &Ws[(p + 1) & 1][(m * 512 + (wv * 64)) * 4]);
            asm volatile("s_waitcnt vmcnt(6)" ::: "memory");  // p's 2 DMA done; ax(4)+next(2) in flight
        } else {
            asm volatile("s_waitcnt vmcnt(4)" ::: "memory");  // p's 2 DMA done; ax(4) in flight
        }
        __builtin_amdgcn_s_barrier();
        __builtin_amdgcn_sched_barrier(0);

        // ---- convert: fp32 scratch -> bf16 image (2 granules/thread) ----
#pragma unroll
        for (int m = 0; m < 2; ++m) {
            const int slot = m * 512 + t;          // = pl
            const f4a v = *(const f4a*)&Ws[p & 1][slot * 4];
#pragma unroll
            for (int u = 0; u < 4; ++u)
                Im[u][slot] = f2bf(v[u]);
        }
        asm volatile("s_waitcnt lgkmcnt(0)" ::: "memory");
        __builtin_amdgcn_s_barrier();
        __builtin_amdgcn_sched_barrier(0);

        // ---- compute: 8 dense 1-KB frag reads + 8 MFMA ----
#pragma unroll
        for (int u = 0; u < 4; ++u) {
            const int d  = p * 4 + u;
            const int jj = d / 9;
#pragma unroll
            for (int nt = 0; nt < 2; ++nt) {
                const v8bf bfr = *(const v8bf*)&Im[u][(nt * 16 + lm) * 32 + q * 8];
                acc[jj][nt] = __builtin_amdgcn_mfma_f32_16x16x32_bf16(
                    ax[u], bfr, acc[jj][nt], 0, 0, 0);
            }
        }
        // next phase's first barrier separates these Im reads from its writes
    }

    // ---- epilogue: fp32 out + bias; 16-B aligned 16-B runs per (b,o) ----
    // D layout: col = lane&15 -> o_local, row = q*4+r2 -> b_local
#pragma unroll
    for (int nt = 0; nt < 2; ++nt) {
        const int o = o0 + nt * 16 + lm;
        const f4a bv = *(const f4a*)(bias + (size_t)o * NPOS + posbase);
#pragma unroll
        for (int r2 = 0; r2 < 4; ++r2) {
            const int b = wv * 16 + q * 4 + r2;
            f4a val = {acc[0][nt][r2] + bv[0], acc[1][nt][r2] + bv[1],
                       acc[2][nt][r2] + bv[2], acc[3][nt][r2] + bv[3]};
            *(f4a*)(out + ((size_t)b * O_ + o) * NPOS + posbase) = val;
        }
    }
}

// ---------------------------------------------------------------------------
// Fallback (no workspace): per-pos kernel gathering straight from fp32.
// ---------------------------------------------------------------------------
__global__ __launch_bounds__(256) void lc_fallback(const float* __restrict__ x,
                                                   const float* __restrict__ weight,
                                                   const float* __restrict__ bias,
                                                   float* __restrict__ out) {
    const int pos = blockIdx.x;
    const int i = pos >> 5, j = pos & 31;
    const int t  = threadIdx.x;
    const int wv = t >> 6;
    const int l  = t & 63;
    const int lm = l & 15;
    const int q  = l >> 4;

    float bv[4];
#pragma unroll
    for (int nt = 0; nt < 4; ++nt)
        bv[nt] = bias[(size_t)(nt * 16 + lm) * NPOS + pos];

    v4f acc[2][4];
#pragma unroll
    for (int a = 0; a < 2; ++a)
#pragma unroll
        for (int n = 0; n < 4; ++n) acc[a][n] = (v4f){0.f, 0.f, 0.f, 0.f};

    for (int k = 0; k < K9; ++k) {
        const int kh = k / 3, kw = k % 3;
        v8bf af[2], bfr[4];
#pragma unroll
        for (int mt = 0; mt < 2; ++mt) {
            const int b = wv * 32 + mt * 16 + lm;
            union { v8bf v; unsigned short s[8]; } u;
#pragma unroll
            for (int cc = 0; cc < 8; ++cc)
                u.s[cc] = f2bf(x[(((size_t)b * C_ + q * 8 + cc) * H_ + (i + kh)) * H_ + (j + kw)]);
            af[mt] = u.v;
        }
#pragma unroll
        for (int nt = 0; nt < 4; ++nt) {
            union { v8bf v; unsigned short s[8]; } u;
#pragma unroll
            for (int cc = 0; cc < 8; ++cc) {
                const int p = (nt * 16 + lm) * C_ + q * 8 + cc;
                u.s[cc] = f2bf(weight[((size_t)p * NPOS + pos) * K9 + k]);
            }
            bfr[nt] = u.v;
        }
#pragma unroll
        for (int mt = 0; mt < 2; ++mt)
#pragma unroll
            for (int nt = 0; nt < 4; ++nt)
                acc[mt][nt] = __builtin_amdgcn_mfma_f32_16x16x32_bf16(
                    af[mt], bfr[nt], acc[mt][nt], 0, 0, 0);
    }
#pragma unroll
    for (int mt = 0; mt < 2; ++mt)
#pragma unroll
        for (int nt = 0; nt < 4; ++nt) {
            const int o = nt * 16 + lm;
#pragma unroll
            for (int r = 0; r < 4; ++r) {
                const int b = wv * 32 + mt * 16 + q * 4 + r;
                out[(size_t)(b * O_ + o) * NPOS + pos] = acc[mt][nt][r] + bv[nt];
            }
        }
}

// ---------------------------------------------------------------------------
extern "C" void kernel_launch(void* const* d_in, const int* in_sizes, int n_in,
                              void* d_out, int out_size, void* d_ws, size_t ws_size,
                              hipStream_t stream) {
    const float* x      = (const float*)d_in[0];
    const float* weight = (const float*)d_in[1];
    const float* bias   = (const float*)d_in[2];
    float* out          = (float*)d_out;

    const size_t X2B = (size_t)H_ * H_ * BC * sizeof(unsigned short);     // 9,469,952

    if (ws_size >= X2B) {
        unsigned short* x2 = (unsigned short*)d_ws;
        repack_x<<<64 * 17, 256, 0, stream>>>(x, x2);
        lc_fused8<<<512, 512, 0, stream>>>(x2, weight, bias, out);
    } else {
        lc_fallback<<<NPOS, 256, 0, stream>>>(x, weight, bias, out);
    }
}

// Round 8
// 188.331 us; speedup vs baseline: 1.1667x; 1.1667x over previous
//
#include <hip/hip_runtime.h>
#include <cstdint>
#include <cstddef>

// Problem constants
#define B_    128   // batch
#define C_    32    // in channels
#define O_    64    // out channels
#define H_    34    // input H=W (34 = 32+2)
#define NPOS  1024  // 32*32 spatial positions
#define K9    9     // 3x3 taps
#define BC    (B_ * C_)   // 4096
#define NPK   (NPOS * K9) // 9216 floats per (o,c) weight row
#define W2IMG (144 * 512) // shorts per block image

typedef __bf16 v8bf __attribute__((ext_vector_type(8)));
typedef float  v4f  __attribute__((ext_vector_type(4)));
typedef float  f4a  __attribute__((ext_vector_type(4)));
typedef unsigned short u16x8 __attribute__((ext_vector_type(8)));
typedef unsigned short u16x4 __attribute__((ext_vector_type(4)));

__device__ __forceinline__ unsigned short f2bf(float f) {
    union { float f; unsigned int u; } v; v.f = f;
    unsigned int u = v.u;
    return (unsigned short)((u + 0x7FFFu + ((u >> 16) & 1u)) >> 16);
}

// 16-B global -> LDS DMA (dest = wave-uniform base + lane*16)
__device__ __forceinline__ void dma16(const void* g, void* l) {
    __builtin_amdgcn_global_load_lds(
        (const __attribute__((address_space(1))) unsigned int*)g,
        (__attribute__((address_space(3))) unsigned int*)l, 16, 0, 0);
}

// ---------------------------------------------------------------------------
// Pass 1: repack x (fp32 [b][c][34][34]) -> x2 (bf16 [h][w][b][c]). [unchanged]
// ---------------------------------------------------------------------------
__global__ __launch_bounds__(256) void repack_x(const float* __restrict__ x,
                                                unsigned short* __restrict__ x2) {
    const int bq = blockIdx.x / 17;
    const int hp = blockIdx.x % 17;
    const int b0 = bq * 2;
    const int h0 = hp * 2;
    __shared__ unsigned short tile[2][H_][66];
    const int t = threadIdx.x;

    for (int e = t; e < 2176; e += 256) {
        const int bb  = e / 1088;
        const int rem = e % 1088;
        const int c   = rem / 34;
        const int wp  = rem % 34;
        const float2 v = *(const float2*)(x +
            ((size_t)((b0 + bb) * C_ + c) * H_ + h0) * H_ + wp * 2);
        const int hh = (wp >= 17) ? 1 : 0;
        const int w  = wp * 2 - hh * 34;
        const int idx = bb * 32 + c;
        tile[hh][w][idx]     = f2bf(v.x);
        tile[hh][w + 1][idx] = f2bf(v.y);
    }
    __syncthreads();

    for (int e = t; e < 2176; e += 256) {
        const int hh  = e / 1088;
        const int rem = e % 1088;
        const int w   = rem >> 5;
        const int i2  = rem & 31;
        ushort2 pk;
        pk.x = tile[hh][w][i2 * 2];
        pk.y = tile[hh][w][i2 * 2 + 1];
        *(ushort2*)(x2 + (size_t)((h0 + hh) * H_ + w) * BC + bq * 64 + i2 * 2) = pk;
    }
}

// ---------------------------------------------------------------------------
// Pass 1b: repack_w — SEQUENTIAL-read weight transpose to W2 bf16.
// weight fp32 [o][c][i][j][k]  ->  W2[blk][d][pl] bf16, where
//   blk = i*8 + jh*4 + oq   (jh = j>>4, oq = o>>4)
//   d   = (j&15)*9 + k      (0..143)
//   pl  = (o&15)*32 + c     (0..511)
// Each lc block's image = 147,456 B CONTIGUOUS.
// Block = (o, i-quarter): reads are long contiguous fp32 runs (576 floats per
// (c, i-pair) = the proven >6 TB/s stream pattern); LDS transpose; writes are
// 64-B aligned 64-B runs (32 pl shorts).
// ---------------------------------------------------------------------------
__global__ __launch_bounds__(512) void repack_w(const float* __restrict__ weight,
                                                unsigned short* __restrict__ w2) {
    __shared__ __align__(16) unsigned short tile[2][32][292];   // 37,376 B (+pad)
    const int o  = blockIdx.x >> 2;       // 0..63
    const int iq = blockIdx.x & 3;        // 0..3
    const int oq = o >> 4, ol = o & 15;
    const int t  = threadIdx.x;

    for (int ip = 0; ip < 4; ++ip) {
        const int i0 = iq * 8 + ip * 2;   // i-pair base
        // ---- read: 32 c x 576 contiguous floats (i-pair, all j,k) ----
        for (int e = t; e < 4608; e += 512) {
            const int c = e / 144, f = e % 144;
            const f4a v = *(const f4a*)(weight +
                ((size_t)(o * 32 + c) * 1024 + i0 * 32) * 9 + 4 * f);
            const int flat = 4 * f;          // 0..572, no ii straddle (288|4)
            const int ii = flat / 288, jk = flat % 288;
            u16x4 pk;
#pragma unroll
            for (int u = 0; u < 4; ++u) pk[u] = f2bf(v[u]);
            *(u16x4*)&tile[ii][c][jk] = pk;
        }
        __syncthreads();
        // ---- write: 2 ii x 2 jh x 144 d tasks, each a 64-B pl-run ----
        for (int e = t; e < 576; e += 512) {
            const int ii = e / 288, rem = e % 288;
            const int jh = rem / 144, d = rem % 144;
            const int jk = jh * 144 + d;     // = j*9+k
            unsigned short* dst = w2 +
                ((size_t)((i0 + ii) * 8 + jh * 4 + oq) * 144 + d) * 512 + ol * 32;
#pragma unroll
            for (int s = 0; s < 4; ++s) {
                u16x8 pk;
#pragma unroll
                for (int u = 0; u < 8; ++u) pk[u] = tile[ii][s * 8 + u][jk];
                *(u16x8*)(dst + s * 8) = pk;
            }
        }
        __syncthreads();
    }
}

// ---------------------------------------------------------------------------
// Main (v9): contiguous-image DMA staging.  Block = (i, j-half, o-quarter),
// grid 256, 512 thr, LDS = one 147,456-B image (1 block/CU by design — the
// 18 up-front global_load_lds wave-instrs put the whole image in flight; no
// VGPR round-trip, no swizzle: DMA dest linear, frag reads contiguous
// 1 KB/wave = conflict-free).  Two-half pipeline: vmcnt(9) -> compute jj 0..7
// while second half lands -> vmcnt(0) -> compute jj 8..15.
// Epilogue: full 64-B out lines per (b,o) (16 consecutive pos).
// ---------------------------------------------------------------------------
__global__ __launch_bounds__(512, 1) void lc_fused9(const unsigned short* __restrict__ x2,
                                                    const unsigned short* __restrict__ w2,
                                                    const float* __restrict__ bias,
                                                    float* __restrict__ out) {
    __shared__ __align__(16) unsigned short Im[W2IMG];   // 147,456 B

    const int bid = blockIdx.x;
    const int lb  = (bid & 7) * 32 + (bid >> 3);   // bijective (256 % 8 == 0)
    const int i   = lb >> 3;            // 0..31
    const int jh  = (lb >> 2) & 1;      // 0..1
    const int oq  = lb & 3;             // 0..3
    const int j0  = jh * 16;
    const int posbase = i * 32 + j0;    // multiple of 16 -> 64-B out lines
    const int t  = threadIdx.x;
    const int wv = t >> 6, l = t & 63, lm = l & 15, q = l >> 4;

    // ---- prologue: issue ALL 18 DMA rounds (8 KB each, linear) ----
    const unsigned short* wsrc = w2 + (size_t)lb * W2IMG;
#pragma unroll
    for (int r = 0; r < 18; ++r)
        dma16(wsrc + (size_t)(r * 512 + t) * 8, &Im[(r * 512 + wv * 64) * 8]);

    v4f acc[16];
#pragma unroll
    for (int a = 0; a < 16; ++a) acc[a] = (v4f){0.f, 0.f, 0.f, 0.f};

#pragma unroll
    for (int h = 0; h < 2; ++h) {
        if (h == 0) asm volatile("s_waitcnt vmcnt(9)" ::: "memory");  // rows 0..71 in
        else        asm volatile("s_waitcnt vmcnt(0)" ::: "memory");  // all in
        __builtin_amdgcn_s_barrier();
        __builtin_amdgcn_sched_barrier(0);

#pragma unroll
        for (int kh = 0; kh < 3; ++kh) {
            v8bf ax[10];
            const int rowbase = (i + kh) * H_ + j0 + h * 8;
#pragma unroll
            for (int w6 = 0; w6 < 10; ++w6)
                ax[w6] = *(const v8bf*)(x2 + (size_t)(rowbase + w6) * BC +
                                        (wv * 16 + lm) * C_ + q * 8);
#pragma unroll
            for (int kw = 0; kw < 3; ++kw) {
#pragma unroll
                for (int jjl = 0; jjl < 8; ++jjl) {
                    const int jj = h * 8 + jjl;
                    const int d  = jj * 9 + kh * 3 + kw;   // image row
                    const v8bf bfr = *(const v8bf*)&Im[d * 512 + lm * 32 + q * 8];
                    acc[jj] = __builtin_amdgcn_mfma_f32_16x16x32_bf16(
                        ax[jjl + kw], bfr, acc[jj], 0, 0, 0);
                }
            }
        }
    }

    // ---- epilogue: fp32 out + bias; FULL 64-B lines per (b,o) ----
    const int o = oq * 16 + lm;
    const float* bp = bias + (size_t)o * NPOS + posbase;
    f4a bv[4];
#pragma unroll
    for (int s = 0; s < 4; ++s) bv[s] = *(const f4a*)(bp + 4 * s);
#pragma unroll
    for (int r2 = 0; r2 < 4; ++r2) {
        const int b = wv * 16 + q * 4 + r2;
        float* op = out + ((size_t)b * O_ + o) * NPOS + posbase;
#pragma unroll
        for (int s = 0; s < 4; ++s) {
            f4a v = {acc[s * 4 + 0][r2] + bv[s][0], acc[s * 4 + 1][r2] + bv[s][1],
                     acc[s * 4 + 2][r2] + bv[s][2], acc[s * 4 + 3][r2] + bv[s][3]};
            *(f4a*)(op + 4 * s) = v;
        }
    }
}

// ---------------------------------------------------------------------------
// Fallback (no workspace): per-pos kernel gathering straight from fp32.
// ---------------------------------------------------------------------------
__global__ __launch_bounds__(256) void lc_fallback(const float* __restrict__ x,
                                                   const float* __restrict__ weight,
                                                   const float* __restrict__ bias,
                                                   float* __restrict__ out) {
    const int pos = blockIdx.x;
    const int i = pos >> 5, j = pos & 31;
    const int t  = threadIdx.x;
    const int wv = t >> 6;
    const int l  = t & 63;
    const int lm = l & 15;
    const int q  = l >> 4;

    float bv[4];
#pragma unroll
    for (int nt = 0; nt < 4; ++nt)
        bv[nt] = bias[(size_t)(nt * 16 + lm) * NPOS + pos];

    v4f acc[2][4];
#pragma unroll
    for (int a = 0; a < 2; ++a)
#pragma unroll
        for (int n = 0; n < 4; ++n) acc[a][n] = (v4f){0.f, 0.f, 0.f, 0.f};

    for (int k = 0; k < K9; ++k) {
        const int kh = k / 3, kw = k % 3;
        v8bf af[2], bfr[4];
#pragma unroll
        for (int mt = 0; mt < 2; ++mt) {
            const int b = wv * 32 + mt * 16 + lm;
            union { v8bf v; unsigned short s[8]; } u;
#pragma unroll
            for (int cc = 0; cc < 8; ++cc)
                u.s[cc] = f2bf(x[(((size_t)b * C_ + q * 8 + cc) * H_ + (i + kh)) * H_ + (j + kw)]);
            af[mt] = u.v;
        }
#pragma unroll
        for (int nt = 0; nt < 4; ++nt) {
            union { v8bf v; unsigned short s[8]; } u;
#pragma unroll
            for (int cc = 0; cc < 8; ++cc) {
                const int p = (nt * 16 + lm) * C_ + q * 8 + cc;
                u.s[cc] = f2bf(weight[((size_t)p * NPOS + pos) * K9 + k]);
            }
            bfr[nt] = u.v;
        }
#pragma unroll
        for (int mt = 0; mt < 2; ++mt)
#pragma unroll
            for (int nt = 0; nt < 4; ++nt)
                acc[mt][nt] = __builtin_amdgcn_mfma_f32_16x16x32_bf16(
                    af[mt], bfr[nt], acc[mt][nt], 0, 0, 0);
    }
#pragma unroll
    for (int mt = 0; mt < 2; ++mt)
#pragma unroll
        for (int nt = 0; nt < 4; ++nt) {
            const int o = nt * 16 + lm;
#pragma unroll
            for (int r = 0; r < 4; ++r) {
                const int b = wv * 32 + mt * 16 + q * 4 + r;
                out[(size_t)(b * O_ + o) * NPOS + pos] = acc[mt][nt][r] + bv[nt];
            }
        }
}

// ---------------------------------------------------------------------------
extern "C" void kernel_launch(void* const* d_in, const int* in_sizes, int n_in,
                              void* d_out, int out_size, void* d_ws, size_t ws_size,
                              hipStream_t stream) {
    const float* x      = (const float*)d_in[0];
    const float* weight = (const float*)d_in[1];
    const float* bias   = (const float*)d_in[2];
    float* out          = (float*)d_out;

    const size_t X2B = (size_t)H_ * H_ * BC * sizeof(unsigned short);     //  9,469,952
    const size_t W2B = (size_t)256 * W2IMG * sizeof(unsigned short);      // 37,748,736

    if (ws_size >= X2B + W2B) {
        unsigned short* x2 = (unsigned short*)d_ws;
        unsigned short* w2 = (unsigned short*)((char*)d_ws + X2B);
        repack_x<<<64 * 17, 256, 0, stream>>>(x, x2);
        repack_w<<<256, 512, 0, stream>>>(weight, w2);
        lc_fused9<<<256, 512, 0, stream>>>(x2, w2, bias, out);
    } else {
        lc_fallback<<<NPOS, 256, 0, stream>>>(x, weight, bias, out);
    }
}